// Round 12
// baseline (281.801 us; speedup 1.0000x reference)
//
#include <hip/hip_runtime.h>

#define NPTS 8192
#define DIM 64
#define BATCH 2
#define KOUT 17
#define QCAP 40     // queue capacity per (row, seg)
#define THRANK 24   // theta = 25th smallest of the 64-subset (margin for 12-bit packing)

typedef float f32x4 __attribute__((ext_vector_type(4)));
typedef short short8 __attribute__((ext_vector_type(8)));
typedef unsigned int uint4v __attribute__((ext_vector_type(4)));

#define MFMA16(A, B, C) __builtin_amdgcn_mfma_f32_16x16x32_bf16(A, B, C, 0, 0, 0)

__device__ __forceinline__ void gload16(const void* g, void* lds) {
  __builtin_amdgcn_global_load_lds((const __attribute__((address_space(1))) void*)g,
                                   (__attribute__((address_space(3))) void*)lds, 16, 0, 0);
}

// ---------- prep: permuted hi/lo bf16 (phl), contiguous f32 (pct), 0.5*|x|^2 ----------
__global__ __launch_bounds__(256)
void prep_kernel(const float* __restrict__ pc, ushort* __restrict__ phl,
                 float* __restrict__ pct, float* __restrict__ sq) {
  __shared__ double psum[256];
  int t = threadIdx.x;
  int u = t >> 5;           // 0..7  (dims u*8 .. u*8+7)
  int p = t & 31;           // 0..31 (point within block)
  int i = blockIdx.x * 32 + p;   // 0..16383
  int b = i >> 13, n = i & (NPTS - 1);
  const float* g = pc + (size_t)b * DIM * NPTS + n;

  float x[8];
  short8 hv, lv;
  double s = 0.0;
  #pragma unroll
  for (int e = 0; e < 8; ++e) {
    x[e] = g[(size_t)(u * 8 + e) * NPTS];
    s += (double)x[e] * (double)x[e];
    unsigned uu = __float_as_uint(x[e]);
    unsigned r = uu + (0x7fffu + ((uu >> 16) & 1));
    unsigned hi = r >> 16;                       // bf16 RNE
    float xl = x[e] - __uint_as_float(hi << 16);
    unsigned ul = __float_as_uint(xl);
    unsigned rl = ul + (0x7fffu + ((ul >> 16) & 1));
    hv[e] = (short)(hi & 0xffffu);
    lv[e] = (short)((rl >> 16) & 0xffffu);
  }
  int slot = u ^ (n & 7);
  ushort* ph = phl + (size_t)i * 128;
  *(short8*)(ph + slot * 8) = hv;
  *(short8*)(ph + 64 + slot * 8) = lv;
  f32x4 v0 = {x[0], x[1], x[2], x[3]}, v1 = {x[4], x[5], x[6], x[7]};
  *(f32x4*)(pct + (size_t)i * 64 + u * 8) = v0;
  *(f32x4*)(pct + (size_t)i * 64 + u * 8 + 4) = v1;

  psum[u * 32 + p] = s;
  __syncthreads();
  if (t < 32) {
    double acc = 0.0;
    #pragma unroll
    for (int uu = 0; uu < 8; ++uu) acc += psum[uu * 32 + t];
    sq[blockIdx.x * 32 + t] = (float)(0.5 * acc);   // HALF |x|^2
  }
}

// ---------- SINGLE-pass MFMA distance + index-packed per-lane top-8 + theta dump ----------
// 1024 blocks x 256 threads; XCD-partitioned mapping (orig&7 -> (b,seg,row-parity)).
// Block = 32 rows x 4096 cols (64 tiles of 64 cols). Wave w owns cols w*16..+15 of each
// tile AND stages exactly that quarter -> no cross-wave LDS dependency -> no barriers.
// packed key = (bits(0.5|c|^2 - <r,c>) & 0xFFFFF000) | (col - colbase); selection is done
// entirely in packed order; f64 refine restores exact ordering from candidates.
__global__ __launch_bounds__(256, 3)
void knn_kernel(const ushort* __restrict__ phl, const float* __restrict__ sq,
                ushort* __restrict__ cand) {
  __shared__ ushort Bt[2][64 * 128];   // 32 KB double buffer (aliased KT/KT2 in theta phase)
  __shared__ float TH[32];
  __shared__ int CNT[32];
  __shared__ ushort QU[32][QCAP];

  int t = threadIdx.x;
  int lane = t & 63;
  int w = t >> 6;
  int orig = blockIdx.x;
  int x8 = orig & 7;
  int b = x8 >> 2;
  int seg = (x8 >> 1) & 1;
  int row0 = ((orig >> 3) * 2 + (x8 & 1)) * 32;
  const ushort* pb = phl + (size_t)b * NPTS * 128;
  const float* sqb = sq + b * NPTS;

  int c15 = lane & 15, l4 = lane >> 4;
  int sw8 = c15 & 7;
  int so0 = (l4 ^ sw8) * 8;          // kk=0 slot offset (ushorts)
  int so1 = ((4 + l4) ^ sw8) * 8;    // kk=1
  int colbase = seg * 4096;
  int lp = w * 16 + c15;             // tile-local col owned by this lane

  // A fragments [hl][kk][rg], rows row0 + rg*16 + c15, sign-flipped (exact)
  short8 a[2][2][2];
  #pragma unroll
  for (int rg = 0; rg < 2; ++rg) {
    int n = row0 + rg * 16 + c15;
    const ushort* pr = pb + (size_t)n * 128;
    #pragma unroll
    for (int hl = 0; hl < 2; ++hl)
      #pragma unroll
      for (int kk = 0; kk < 2; ++kk) {
        int slot = (kk * 4 + l4) ^ (n & 7);
        short8 v = *(const short8*)(pr + hl * 64 + slot * 8);
        uint4v uv = *(uint4v*)&v;
        uv ^= 0x80008000u;
        a[hl][kk][rg] = *(short8*)&uv;
      }
  }

  // wave w stages its own 16 points (4 KB) of the tile: 4 x gload16, 1 KB each
#define STAGE(BUF, TILE) do { \
    const ushort* src_ = pb + (size_t)(colbase + (TILE) * 64 + w * 16 + (lane >> 4)) * 128 + (lane & 15) * 8; \
    ushort* dst_ = &Bt[BUF][w * 16 * 128]; \
    gload16(src_,        dst_); \
    gload16(src_ + 512,  dst_ + 512); \
    gload16(src_ + 1024, dst_ + 1024); \
    gload16(src_ + 1536, dst_ + 1536); \
  } while (0)

#define COMPKEYS(BUF, SQV, C0, C1) \
    const ushort* bt_ = &Bt[BUF][lp * 128]; \
    short8 bh0 = *(const short8*)(bt_ + so0); \
    short8 bl0 = *(const short8*)(bt_ + 64 + so0); \
    short8 bh1 = *(const short8*)(bt_ + so1); \
    short8 bl1 = *(const short8*)(bt_ + 64 + so1); \
    f32x4 C0 = {SQV, SQV, SQV, SQV}, C1 = C0; \
    C0 = MFMA16(a[0][0][0], bh0, C0); C1 = MFMA16(a[0][0][1], bh0, C1); \
    C0 = MFMA16(a[0][0][0], bl0, C0); C1 = MFMA16(a[0][0][1], bl0, C1); \
    C0 = MFMA16(a[1][0][0], bh0, C0); C1 = MFMA16(a[1][0][1], bh0, C1); \
    C0 = MFMA16(a[0][1][0], bh1, C0); C1 = MFMA16(a[0][1][1], bh1, C1); \
    C0 = MFMA16(a[0][1][0], bl1, C0); C1 = MFMA16(a[0][1][1], bl1, C1); \
    C0 = MFMA16(a[1][1][0], bh1, C0); C1 = MFMA16(a[1][1][1], bh1, C1);

  // packed sorted top-8 lists per (rowgroup, r): 64 VGPR, static indices only
  float L0[4][8], L1[4][8];
  const float BIG = __uint_as_float(0x7F000000u);
  #pragma unroll
  for (int r = 0; r < 4; ++r)
    #pragma unroll
    for (int s = 0; s < 8; ++s) { L0[r][s] = BIG; L1[r][s] = BIG; }

#define INSERT8(C0, C1, CID) do { \
    _Pragma("unroll") \
    for (int r = 0; r < 4; ++r) { \
      float p0 = __uint_as_float((__float_as_uint(C0[r]) & 0xFFFFF000u) | (CID)); \
      _Pragma("unroll") \
      for (int s = 0; s < 8; ++s) { float mn_ = fminf(L0[r][s], p0); p0 = fmaxf(L0[r][s], p0); L0[r][s] = mn_; } \
      float p1 = __uint_as_float((__float_as_uint(C1[r]) & 0xFFFFF000u) | (CID)); \
      _Pragma("unroll") \
      for (int s = 0; s < 8; ++s) { float mn_ = fminf(L1[r][s], p1); p1 = fmaxf(L1[r][s], p1); L1[r][s] = mn_; } \
    } \
  } while (0)

  // ================= single pass over 64 tiles =================
  asm volatile("s_waitcnt vmcnt(0)" ::: "memory");
  STAGE(0, 0);
  float sqCur = sqb[colbase + lp];
  unsigned colid = (unsigned)lp;     // seg-relative col, 12 bits
  for (int tt = 0; tt < 63; ++tt) {
    int cur = tt & 1;
    STAGE(cur ^ 1, tt + 1);
    float sqNxt = sqb[colbase + (tt + 1) * 64 + lp];
    asm volatile("s_waitcnt vmcnt(5)" ::: "memory");
    COMPKEYS(cur, sqCur, c0, c1);
    INSERT8(c0, c1, colid);
    colid += 64;
    sqCur = sqNxt;
  }
  {
    asm volatile("s_waitcnt vmcnt(0)" ::: "memory");
    COMPKEYS(1, sqCur, c0, c1);
    INSERT8(c0, c1, colid);
  }

  // ================= subset: KT[32][128] -> pair-merge KT2[32][64] (alias dbuf) =================
  __syncthreads();
  float* KT = (float*)&Bt[0][0];    // 16 KB
  float* KT2 = (float*)&Bt[1][0];   // 8 KB
  #pragma unroll
  for (int r = 0; r < 4; ++r) {
    int row = l4 * 4 + r;
    int cpos = (w * 16 + c15) * 2;
    KT[row * 128 + cpos] = L0[r][0];
    KT[row * 128 + cpos + 1] = L0[r][1];
    KT[(row + 16) * 128 + cpos] = L1[r][0];
    KT[(row + 16) * 128 + cpos + 1] = L1[r][1];
  }
  __syncthreads();
  #pragma unroll
  for (int it = 0; it < 4; ++it) {
    int idx = t + it * 256;               // 0..1023
    int row = idx >> 5, j = idx & 31;
    float a1 = KT[row * 128 + j * 2], a2 = KT[row * 128 + j * 2 + 1];
    float b1 = KT[row * 128 + 64 + j * 2], b2 = KT[row * 128 + 64 + j * 2 + 1];
    KT2[row * 64 + j * 2] = fminf(a1, b1);
    KT2[row * 64 + j * 2 + 1] = fminf(fmaxf(a1, b1), fminf(a2, b2));
  }
  __syncthreads();

  // ================= theta per row = (THRANK+1)-th smallest of 64-subset =================
  {
    int row = t >> 3;
    int j0 = (t & 7) * 8;
    const f32x4* vr4 = (const f32x4*)(KT2 + row * 64);
    float vj[8];
    *(f32x4*)vj = vr4[(t & 7) * 2];
    *(f32x4*)(vj + 4) = vr4[(t & 7) * 2 + 1];
    int rank[8];
    #pragma unroll
    for (int jj = 0; jj < 8; ++jj) rank[jj] = 0;
    for (int m4 = 0; m4 < 16; ++m4) {
      f32x4 vm = vr4[m4];
      #pragma unroll
      for (int e = 0; e < 4; ++e) {
        int m = m4 * 4 + e;
        float ve = vm[e];
        #pragma unroll
        for (int jj = 0; jj < 8; ++jj)
          rank[jj] += (ve < vj[jj] || (ve == vj[jj] && m < j0 + jj)) ? 1 : 0;
      }
    }
    #pragma unroll
    for (int jj = 0; jj < 8; ++jj)
      if (rank[jj] == THRANK) TH[row] = vj[jj];
    if (t < 32) CNT[t] = 0;
  }
  __syncthreads();
  float th0[4], th1[4];
  #pragma unroll
  for (int r = 0; r < 4; ++r) { th0[r] = TH[l4 * 4 + r]; th1[r] = TH[16 + l4 * 4 + r]; }

  // ================= dump candidates straight from list registers =================
  #pragma unroll
  for (int r = 0; r < 4; ++r) {
    #pragma unroll
    for (int s = 0; s < 8; ++s) {
      if (L0[r][s] <= th0[r]) {
        int rw = l4 * 4 + r;
        int pos = atomicAdd(&CNT[rw], 1);
        if (pos < QCAP) QU[rw][pos] = (ushort)((__float_as_uint(L0[r][s]) & 0xFFFu) + colbase);
      }
      if (L1[r][s] <= th1[r]) {
        int rw = 16 + l4 * 4 + r;
        int pos = atomicAdd(&CNT[rw], 1);
        if (pos < QCAP) QU[rw][pos] = (ushort)((__float_as_uint(L1[r][s]) & 0xFFFu) + colbase);
      }
    }
  }

  // ================= pad + dump queues =================
  __syncthreads();
  for (int i = t; i < 32 * QCAP; i += 256) {
    int row = i / QCAP, s2 = i % QCAP;
    int c2 = CNT[row]; if (c2 > QCAP) c2 = QCAP;
    ushort v = (s2 < c2) ? QU[row][s2] : (ushort)0xFFFFu;
    cand[((size_t)(b * NPTS + row0 + row) * 2 + seg) * QCAP + s2] = v;
  }
}

// ---------- exact f64 re-rank of up to 80 candidates, wave per point ----------
__global__ void refine_kernel(const float* __restrict__ pct, const ushort* __restrict__ cand,
                              int* __restrict__ knn, float* __restrict__ idxf) {
  int gw = (blockIdx.x * 256 + threadIdx.x) >> 6;  // 0..16383
  int lane = threadIdx.x & 63;
  int b = gw >> 13, n = gw & (NPTS - 1);
  const float* pcb = pct + (size_t)b * NPTS * 64;
  const ushort* cb = cand + (size_t)gw * (2 * QCAP);
  const float* qp = pcb + (size_t)n * 64;

  unsigned ciA = cb[lane];
  unsigned ciB = (lane < 2 * QCAP - 64) ? (unsigned)cb[64 + lane] : 0xFFFFu;
  double dA = __builtin_inf(), dB = __builtin_inf();
  if (ciA != 0xFFFFu) {
    const float* cp = pcb + (size_t)ciA * 64;
    double s = 0.0;
    #pragma unroll
    for (int u = 0; u < 16; ++u) {
      f32x4 cv = *(const f32x4*)(cp + u * 4);
      f32x4 qv = *(const f32x4*)(qp + u * 4);
      #pragma unroll
      for (int e = 0; e < 4; ++e) {
        double diff = (double)cv[e] - (double)qv[e];
        s = fma(diff, diff, s);
      }
    }
    dA = s;
  }
  if (ciB != 0xFFFFu) {
    const float* cp = pcb + (size_t)ciB * 64;
    double s = 0.0;
    #pragma unroll
    for (int u = 0; u < 16; ++u) {
      f32x4 cv = *(const f32x4*)(cp + u * 4);
      f32x4 qv = *(const f32x4*)(qp + u * 4);
      #pragma unroll
      for (int e = 0; e < 4; ++e) {
        double diff = (double)cv[e] - (double)qv[e];
        s = fma(diff, diff, s);
      }
    }
    dB = s;
  }

  int rA = 0, rB = 0;
  for (int j = 0; j < 64; ++j) {
    double dk = __shfl(dA, j);
    unsigned ik = (unsigned)__shfl((int)ciA, j);
    rA += ((dk < dA) || (dk == dA && ik < ciA)) ? 1 : 0;
    rB += ((dk < dB) || (dk == dB && ik < ciB)) ? 1 : 0;
  }
  for (int j = 0; j < 2 * QCAP - 64; ++j) {
    double dk = __shfl(dB, j);
    unsigned ik = (unsigned)__shfl((int)ciB, j);
    rA += ((dk < dA) || (dk == dA && ik < ciA)) ? 1 : 0;
    rB += ((dk < dB) || (dk == dB && ik < ciB)) ? 1 : 0;
  }
  if (ciA != 0xFFFFu && rA < KOUT) {
    size_t o = ((size_t)b * KOUT + rA) * NPTS + n;
    knn[o] = (int)ciA;
    idxf[o] = (float)ciA;
  }
  if (lane < 2 * QCAP - 64 && ciB != 0xFFFFu && rB < KOUT) {
    size_t o = ((size_t)b * KOUT + rB) * NPTS + n;
    knn[o] = (int)ciB;
    idxf[o] = (float)ciB;
  }
}

// ---------- edge features: out [B][128][17][N]; thread handles 4 n-values (float4) ----------
__global__ __launch_bounds__(256)
void edge_kernel(const float* __restrict__ pc, const int* __restrict__ knn,
                 float* __restrict__ out) {
  int n = (blockIdx.x * 256 + threadIdx.x) * 4;
  int z = blockIdx.y;
  int b = z >> 6, c = z & 63;
  const float* row = pc + ((size_t)b * DIM + c) * NPTS;
  f32x4 central = *(const f32x4*)(row + n);
  size_t base = (((size_t)b * 2 * DIM + c) * KOUT) * NPTS + n;
  const int* kb = knn + (size_t)b * KOUT * NPTS + n;
  #pragma unroll
  for (int k = 0; k < KOUT; ++k) {
    int4 nb = *(const int4*)(kb + (size_t)k * NPTS);
    f32x4 nv = {row[nb.x], row[nb.y], row[nb.z], row[nb.w]};
    *(f32x4*)(out + base + (size_t)k * NPTS) = central;
    *(f32x4*)(out + base + (size_t)(DIM * KOUT + k) * NPTS) = nv - central;
  }
}

extern "C" void kernel_launch(void* const* d_in, const int* in_sizes, int n_in,
                              void* d_out, int out_size, void* d_ws, size_t ws_size,
                              hipStream_t stream) {
  const float* pc = (const float*)d_in[0];
  float* out = (float*)d_out;
  char* ws = (char*)d_ws;
  ushort* phl = (ushort*)ws;                                     // 4 MB
  float* pct  = (float*)(ws + (size_t)4 * 1024 * 1024);          // 4 MB
  float* sq   = (float*)(ws + (size_t)8 * 1024 * 1024);          // 64 KB
  ushort* cand = (ushort*)(ws + (size_t)8 * 1024 * 1024 + 65536);
  int* knn    = (int*)(ws + (size_t)8 * 1024 * 1024 + 65536 + (size_t)16384 * 2 * QCAP * 2);

  float* idxf = out + (size_t)BATCH * 2 * DIM * KOUT * NPTS;

  prep_kernel<<<512, 256, 0, stream>>>(pc, phl, pct, sq);
  knn_kernel<<<1024, 256, 0, stream>>>(phl, sq, cand);
  refine_kernel<<<4096, 256, 0, stream>>>(pct, cand, knn, idxf);
  edge_kernel<<<dim3(NPTS / 1024, BATCH * DIM), 256, 0, stream>>>(pc, knn, out);
}

// Round 13
// 197.834 us; speedup vs baseline: 1.4244x; 1.4244x over previous
//
#include <hip/hip_runtime.h>

#define NPTS 8192
#define DIM 64
#define BATCH 2
#define KOUT 17
#define QCAP 40     // queue capacity per (row, seg)
#define THRANK 21   // theta = 22nd smallest of the 64-subset
#define THSLACK 0.25f

typedef float f32x4 __attribute__((ext_vector_type(4)));
typedef short short8 __attribute__((ext_vector_type(8)));
typedef unsigned int uint4v __attribute__((ext_vector_type(4)));

#define MFMA16(A, B, C) __builtin_amdgcn_mfma_f32_16x16x32_bf16(A, B, C, 0, 0, 0)

__device__ __forceinline__ void gload16(const void* g, void* lds) {
  __builtin_amdgcn_global_load_lds((const __attribute__((address_space(1))) void*)g,
                                   (__attribute__((address_space(3))) void*)lds, 16, 0, 0);
}

// ---------- prep: permuted hi bf16 (ph), contiguous f32 (pct), 0.5*|x|^2 ----------
__global__ __launch_bounds__(256)
void prep_kernel(const float* __restrict__ pc, ushort* __restrict__ phl,
                 float* __restrict__ pct, float* __restrict__ sq) {
  __shared__ double psum[256];
  int t = threadIdx.x;
  int u = t >> 5;           // 0..7  (dims u*8 .. u*8+7)
  int p = t & 31;           // 0..31 (point within block)
  int i = blockIdx.x * 32 + p;   // 0..16383
  int b = i >> 13, n = i & (NPTS - 1);
  const float* g = pc + (size_t)b * DIM * NPTS + n;

  float x[8];
  short8 hv;
  double s = 0.0;
  #pragma unroll
  for (int e = 0; e < 8; ++e) {
    x[e] = g[(size_t)(u * 8 + e) * NPTS];
    s += (double)x[e] * (double)x[e];
    unsigned uu = __float_as_uint(x[e]);
    unsigned r = uu + (0x7fffu + ((uu >> 16) & 1));
    hv[e] = (short)((r >> 16) & 0xffffu);   // bf16 RNE
  }
  int slot = u ^ (n & 7);
  *(short8*)(phl + (size_t)i * 64 + slot * 8) = hv;
  f32x4 v0 = {x[0], x[1], x[2], x[3]}, v1 = {x[4], x[5], x[6], x[7]};
  *(f32x4*)(pct + (size_t)i * 64 + u * 8) = v0;
  *(f32x4*)(pct + (size_t)i * 64 + u * 8 + 4) = v1;

  psum[u * 32 + p] = s;
  __syncthreads();
  if (t < 32) {
    double acc = 0.0;
    #pragma unroll
    for (int uu = 0; uu < 8; ++uu) acc += psum[uu * 32 + t];
    sq[blockIdx.x * 32 + t] = (float)(0.5 * acc);   // HALF |x|^2
  }
}

// ---------- two-pass hi-only MFMA distance + theta-filter, barrier-free async pipeline ----------
// 1024 blocks x 256 threads; XCD-partitioned mapping (orig&7 -> (b,seg,row-parity)).
// Block = 32 rows x 4096 cols (64 tiles of 64 cols). Wave w owns cols w*16..+15 of each tile
// and stages exactly those -> no cross-wave LDS dependency -> no hot-loop barriers.
// key(row,col) = 0.5*|col|^2 - <hi(row),hi(col)>  (bf16 approx; SAME bits in both passes;
// f64 refine over candidates restores exact order; theta gets +THSLACK margin).
__global__ __launch_bounds__(256, 4)
void knn_kernel(const ushort* __restrict__ phl, const float* __restrict__ sq,
                ushort* __restrict__ cand) {
  __shared__ ushort Bt[2][64 * 64];   // 16 KB double buffer (aliased as KT in theta phase)
  __shared__ float KT2[32 * 64];      // 8 KB
  __shared__ float TH[32];
  __shared__ int CNT[32];
  __shared__ ushort QU[32][QCAP];

  int t = threadIdx.x;
  int lane = t & 63;
  int w = t >> 6;
  int orig = blockIdx.x;
  int x8 = orig & 7;
  int b = x8 >> 2;
  int seg = (x8 >> 1) & 1;
  int row0 = ((orig >> 3) * 2 + (x8 & 1)) * 32;
  const ushort* pb = phl + (size_t)b * NPTS * 64;
  const float* sqb = sq + b * NPTS;

  int c15 = lane & 15, l4 = lane >> 4;
  int sw8 = c15 & 7;
  int so0 = (l4 ^ sw8) * 8;          // kk=0 slot offset (ushorts)
  int so1 = ((4 + l4) ^ sw8) * 8;    // kk=1
  int colbase = seg * 4096;
  int lp = w * 16 + c15;             // tile-local col owned by this lane
  const float* sqp = sqb + colbase + lp;

  // A fragments [kk][rg], rows row0 + rg*16 + c15, sign-flipped (exact)
  short8 a[2][2];
  #pragma unroll
  for (int rg = 0; rg < 2; ++rg) {
    int n = row0 + rg * 16 + c15;
    const ushort* pr = pb + (size_t)n * 64;
    #pragma unroll
    for (int kk = 0; kk < 2; ++kk) {
      int slot = (kk * 4 + l4) ^ (n & 7);
      short8 v = *(const short8*)(pr + slot * 8);
      uint4v uv = *(uint4v*)&v;
      uv ^= 0x80008000u;
      a[kk][rg] = *(short8*)&uv;
    }
  }

  // wave w stages its own 16 points (2 KB) of the tile: 2 x gload16
#define STAGE(BUF, TILE) do { \
    const ushort* src_ = pb + (size_t)(colbase + (TILE) * 64 + w * 16 + (lane >> 3)) * 64 + (lane & 7) * 8; \
    ushort* dst_ = &Bt[BUF][w * 16 * 64]; \
    gload16(src_, dst_); \
    gload16(src_ + 512, dst_ + 512); \
  } while (0)

#define COMPKEYS(BUF, SQV, C0, C1) \
    const ushort* bt_ = &Bt[BUF][lp * 64]; \
    short8 b0 = *(const short8*)(bt_ + so0); \
    short8 b1 = *(const short8*)(bt_ + so1); \
    f32x4 C0 = {SQV, SQV, SQV, SQV}, C1 = C0; \
    C0 = MFMA16(a[0][0], b0, C0); C1 = MFMA16(a[0][1], b0, C1); \
    C0 = MFMA16(a[1][0], b1, C0); C1 = MFMA16(a[1][1], b1, C1);

  // ================= PASS A: per-lane top-2 per owned row =================
  float k1[2][4], k2[2][4];
  #pragma unroll
  for (int rg = 0; rg < 2; ++rg)
    #pragma unroll
    for (int r = 0; r < 4; ++r) { k1[rg][r] = __builtin_inff(); k2[rg][r] = __builtin_inff(); }

#define SELA(C0, C1) { \
    _Pragma("unroll") \
    for (int r = 0; r < 4; ++r) { \
      k2[0][r] = __builtin_amdgcn_fmed3f(C0[r], k1[0][r], k2[0][r]); \
      k1[0][r] = fminf(C0[r], k1[0][r]); \
      k2[1][r] = __builtin_amdgcn_fmed3f(C1[r], k1[1][r], k2[1][r]); \
      k1[1][r] = fminf(C1[r], k1[1][r]); \
    } }

  {
    asm volatile("s_waitcnt vmcnt(0)" ::: "memory");
    STAGE(0, 0);
    float sqA = sqp[0], sqB;
    for (int tt = 0; tt < 62; tt += 2) {
      STAGE(1, tt + 1);
      sqB = sqp[(tt + 1) * 64];
      asm volatile("s_waitcnt vmcnt(3)" ::: "memory");
      { COMPKEYS(0, sqA, c0, c1); SELA(c0, c1); }
      STAGE(0, tt + 2);
      sqA = sqp[(tt + 2) * 64];
      asm volatile("s_waitcnt vmcnt(3)" ::: "memory");
      { COMPKEYS(1, sqB, c0, c1); SELA(c0, c1); }
    }
    STAGE(1, 63);
    sqB = sqp[63 * 64];
    asm volatile("s_waitcnt vmcnt(3)" ::: "memory");
    { COMPKEYS(0, sqA, c0, c1); SELA(c0, c1); }
    asm volatile("s_waitcnt vmcnt(0)" ::: "memory");
    { COMPKEYS(1, sqB, c0, c1); SELA(c0, c1); }
  }

  // ================= subset: KT[32][128] -> pair-merge KT2[32][64] =================
  __syncthreads();
  float* KT = (float*)&Bt[0][0];    // 16 KB (both buffers)
  #pragma unroll
  for (int rg = 0; rg < 2; ++rg)
    #pragma unroll
    for (int r = 0; r < 4; ++r) {
      int row = rg * 16 + l4 * 4 + r;
      KT[row * 128 + (w * 16 + c15) * 2] = k1[rg][r];
      KT[row * 128 + (w * 16 + c15) * 2 + 1] = k2[rg][r];
    }
  __syncthreads();
  #pragma unroll
  for (int it = 0; it < 4; ++it) {
    int idx = t + it * 256;               // 0..1023
    int row = idx >> 5, j = idx & 31;
    float a1 = KT[row * 128 + j * 2], a2 = KT[row * 128 + j * 2 + 1];
    float b1 = KT[row * 128 + 64 + j * 2], b2 = KT[row * 128 + 64 + j * 2 + 1];
    KT2[row * 64 + j * 2] = fminf(a1, b1);
    KT2[row * 64 + j * 2 + 1] = fminf(fmaxf(a1, b1), fminf(a2, b2));
  }
  __syncthreads();

  // ================= theta per row = 22nd smallest of 64-subset (+slack) =================
  {
    int row = t >> 3;
    int j0 = (t & 7) * 8;
    const f32x4* vr4 = (const f32x4*)(KT2 + row * 64);
    float vj[8];
    *(f32x4*)vj = vr4[(t & 7) * 2];
    *(f32x4*)(vj + 4) = vr4[(t & 7) * 2 + 1];
    int rank[8];
    #pragma unroll
    for (int jj = 0; jj < 8; ++jj) rank[jj] = 0;
    for (int m4 = 0; m4 < 16; ++m4) {
      f32x4 vm = vr4[m4];
      #pragma unroll
      for (int e = 0; e < 4; ++e) {
        int m = m4 * 4 + e;
        float ve = vm[e];
        #pragma unroll
        for (int jj = 0; jj < 8; ++jj)
          rank[jj] += (ve < vj[jj] || (ve == vj[jj] && m < j0 + jj)) ? 1 : 0;
      }
    }
    #pragma unroll
    for (int jj = 0; jj < 8; ++jj)
      if (rank[jj] == THRANK) TH[row] = vj[jj];
    if (t < 32) CNT[t] = 0;
  }
  __syncthreads();
  float th0[4], th1[4];
  #pragma unroll
  for (int r = 0; r < 4; ++r) {
    th0[r] = TH[l4 * 4 + r] + THSLACK;
    th1[r] = TH[16 + l4 * 4 + r] + THSLACK;
  }

  // ================= PASS B: recompute (bitwise identical) + collect key<=theta =================
#define SELB(C0, C1, GCOL) { \
    _Pragma("unroll") \
    for (int r = 0; r < 4; ++r) { \
      if (C0[r] <= th0[r]) { \
        int rw = l4 * 4 + r; \
        int pos = atomicAdd(&CNT[rw], 1); \
        if (pos < QCAP) QU[rw][pos] = (ushort)(GCOL); \
      } \
      if (C1[r] <= th1[r]) { \
        int rw = 16 + l4 * 4 + r; \
        int pos = atomicAdd(&CNT[rw], 1); \
        if (pos < QCAP) QU[rw][pos] = (ushort)(GCOL); \
      } \
    } }

  {
    asm volatile("s_waitcnt vmcnt(0)" ::: "memory");
    STAGE(0, 0);
    float sqA = sqp[0], sqB;
    int gc = colbase + lp;
    for (int tt = 0; tt < 62; tt += 2) {
      STAGE(1, tt + 1);
      sqB = sqp[(tt + 1) * 64];
      asm volatile("s_waitcnt vmcnt(3)" ::: "memory");
      { COMPKEYS(0, sqA, c0, c1); SELB(c0, c1, gc); }
      STAGE(0, tt + 2);
      sqA = sqp[(tt + 2) * 64];
      asm volatile("s_waitcnt vmcnt(3)" ::: "memory");
      { COMPKEYS(1, sqB, c0, c1); SELB(c0, c1, gc + 64); }
      gc += 128;
    }
    STAGE(1, 63);
    sqB = sqp[63 * 64];
    asm volatile("s_waitcnt vmcnt(3)" ::: "memory");
    { COMPKEYS(0, sqA, c0, c1); SELB(c0, c1, gc); }
    asm volatile("s_waitcnt vmcnt(0)" ::: "memory");
    { COMPKEYS(1, sqB, c0, c1); SELB(c0, c1, gc + 64); }
  }

  // ================= pad + dump queues =================
  __syncthreads();
  for (int i = t; i < 32 * QCAP; i += 256) {
    int row = i / QCAP, s2 = i % QCAP;
    int c2 = CNT[row]; if (c2 > QCAP) c2 = QCAP;
    ushort v = (s2 < c2) ? QU[row][s2] : (ushort)0xFFFFu;
    cand[((size_t)(b * NPTS + row0 + row) * 2 + seg) * QCAP + s2] = v;
  }
}

// ---------- exact f64 re-rank of up to 80 candidates, wave per point ----------
__global__ void refine_kernel(const float* __restrict__ pct, const ushort* __restrict__ cand,
                              int* __restrict__ knn, float* __restrict__ idxf) {
  int gw = (blockIdx.x * 256 + threadIdx.x) >> 6;  // 0..16383
  int lane = threadIdx.x & 63;
  int b = gw >> 13, n = gw & (NPTS - 1);
  const float* pcb = pct + (size_t)b * NPTS * 64;
  const ushort* cb = cand + (size_t)gw * (2 * QCAP);
  const float* qp = pcb + (size_t)n * 64;

  unsigned ciA = cb[lane];
  unsigned ciB = (lane < 2 * QCAP - 64) ? (unsigned)cb[64 + lane] : 0xFFFFu;
  double dA = __builtin_inf(), dB = __builtin_inf();
  if (ciA != 0xFFFFu) {
    const float* cp = pcb + (size_t)ciA * 64;
    double s = 0.0;
    #pragma unroll
    for (int u = 0; u < 16; ++u) {
      f32x4 cv = *(const f32x4*)(cp + u * 4);
      f32x4 qv = *(const f32x4*)(qp + u * 4);
      #pragma unroll
      for (int e = 0; e < 4; ++e) {
        double diff = (double)cv[e] - (double)qv[e];
        s = fma(diff, diff, s);
      }
    }
    dA = s;
  }
  if (ciB != 0xFFFFu) {
    const float* cp = pcb + (size_t)ciB * 64;
    double s = 0.0;
    #pragma unroll
    for (int u = 0; u < 16; ++u) {
      f32x4 cv = *(const f32x4*)(cp + u * 4);
      f32x4 qv = *(const f32x4*)(qp + u * 4);
      #pragma unroll
      for (int e = 0; e < 4; ++e) {
        double diff = (double)cv[e] - (double)qv[e];
        s = fma(diff, diff, s);
      }
    }
    dB = s;
  }

  int rA = 0, rB = 0;
  for (int j = 0; j < 64; ++j) {
    double dk = __shfl(dA, j);
    unsigned ik = (unsigned)__shfl((int)ciA, j);
    rA += ((dk < dA) || (dk == dA && ik < ciA)) ? 1 : 0;
    rB += ((dk < dB) || (dk == dB && ik < ciB)) ? 1 : 0;
  }
  for (int j = 0; j < 2 * QCAP - 64; ++j) {
    double dk = __shfl(dB, j);
    unsigned ik = (unsigned)__shfl((int)ciB, j);
    rA += ((dk < dA) || (dk == dA && ik < ciA)) ? 1 : 0;
    rB += ((dk < dB) || (dk == dB && ik < ciB)) ? 1 : 0;
  }
  if (ciA != 0xFFFFu && rA < KOUT) {
    size_t o = ((size_t)b * KOUT + rA) * NPTS + n;
    knn[o] = (int)ciA;
    idxf[o] = (float)ciA;
  }
  if (lane < 2 * QCAP - 64 && ciB != 0xFFFFu && rB < KOUT) {
    size_t o = ((size_t)b * KOUT + rB) * NPTS + n;
    knn[o] = (int)ciB;
    idxf[o] = (float)ciB;
  }
}

// ---------- edge features: out [B][128][17][N]; thread handles 4 n-values (float4) ----------
__global__ __launch_bounds__(256)
void edge_kernel(const float* __restrict__ pc, const int* __restrict__ knn,
                 float* __restrict__ out) {
  int n = (blockIdx.x * 256 + threadIdx.x) * 4;
  int z = blockIdx.y;
  int b = z >> 6, c = z & 63;
  const float* row = pc + ((size_t)b * DIM + c) * NPTS;
  f32x4 central = *(const f32x4*)(row + n);
  size_t base = (((size_t)b * 2 * DIM + c) * KOUT) * NPTS + n;
  const int* kb = knn + (size_t)b * KOUT * NPTS + n;
  #pragma unroll
  for (int k = 0; k < KOUT; ++k) {
    int4 nb = *(const int4*)(kb + (size_t)k * NPTS);
    f32x4 nv = {row[nb.x], row[nb.y], row[nb.z], row[nb.w]};
    *(f32x4*)(out + base + (size_t)k * NPTS) = central;
    *(f32x4*)(out + base + (size_t)(DIM * KOUT + k) * NPTS) = nv - central;
  }
}

extern "C" void kernel_launch(void* const* d_in, const int* in_sizes, int n_in,
                              void* d_out, int out_size, void* d_ws, size_t ws_size,
                              hipStream_t stream) {
  const float* pc = (const float*)d_in[0];
  float* out = (float*)d_out;
  char* ws = (char*)d_ws;
  ushort* phl = (ushort*)ws;                                     // 2 MB (hi only)
  float* pct  = (float*)(ws + (size_t)2 * 1024 * 1024);          // 4 MB
  float* sq   = (float*)(ws + (size_t)6 * 1024 * 1024);          // 64 KB
  ushort* cand = (ushort*)(ws + (size_t)6 * 1024 * 1024 + 65536);
  int* knn    = (int*)(ws + (size_t)6 * 1024 * 1024 + 65536 + (size_t)16384 * 2 * QCAP * 2);

  float* idxf = out + (size_t)BATCH * 2 * DIM * KOUT * NPTS;

  prep_kernel<<<512, 256, 0, stream>>>(pc, phl, pct, sq);
  knn_kernel<<<1024, 256, 0, stream>>>(phl, sq, cand);
  refine_kernel<<<4096, 256, 0, stream>>>(pct, cand, knn, idxf);
  edge_kernel<<<dim3(NPTS / 1024, BATCH * DIM), 256, 0, stream>>>(pc, knn, out);
}

// Round 14
// 197.309 us; speedup vs baseline: 1.4282x; 1.0027x over previous
//
#include <hip/hip_runtime.h>

#define NPTS 8192
#define DIM 64
#define BATCH 2
#define KOUT 17
#define QCAP 40     // queue capacity per (row, seg)
#define THRANK 21   // theta = 22nd smallest of the 64-subset
#define THSLACK 0.25f

typedef float f32x4 __attribute__((ext_vector_type(4)));
typedef short short8 __attribute__((ext_vector_type(8)));
typedef unsigned int uint4v __attribute__((ext_vector_type(4)));

#define MFMA16(A, B, C) __builtin_amdgcn_mfma_f32_16x16x32_bf16(A, B, C, 0, 0, 0)

__device__ __forceinline__ void gload16(const void* g, void* lds) {
  __builtin_amdgcn_global_load_lds((const __attribute__((address_space(1))) void*)g,
                                   (__attribute__((address_space(3))) void*)lds, 16, 0, 0);
}

// ---------- prep: permuted hi bf16 (ph), contiguous f32 (pct), 0.5*|x|^2 ----------
__global__ __launch_bounds__(256)
void prep_kernel(const float* __restrict__ pc, ushort* __restrict__ phl,
                 float* __restrict__ pct, float* __restrict__ sq) {
  __shared__ double psum[256];
  int t = threadIdx.x;
  int u = t >> 5;           // 0..7  (dims u*8 .. u*8+7)
  int p = t & 31;           // 0..31 (point within block)
  int i = blockIdx.x * 32 + p;   // 0..16383
  int b = i >> 13, n = i & (NPTS - 1);
  const float* g = pc + (size_t)b * DIM * NPTS + n;

  float x[8];
  short8 hv;
  double s = 0.0;
  #pragma unroll
  for (int e = 0; e < 8; ++e) {
    x[e] = g[(size_t)(u * 8 + e) * NPTS];
    s += (double)x[e] * (double)x[e];
    unsigned uu = __float_as_uint(x[e]);
    unsigned r = uu + (0x7fffu + ((uu >> 16) & 1));
    hv[e] = (short)((r >> 16) & 0xffffu);   // bf16 RNE
  }
  int slot = u ^ (n & 7);
  *(short8*)(phl + (size_t)i * 64 + slot * 8) = hv;
  f32x4 v0 = {x[0], x[1], x[2], x[3]}, v1 = {x[4], x[5], x[6], x[7]};
  *(f32x4*)(pct + (size_t)i * 64 + u * 8) = v0;
  *(f32x4*)(pct + (size_t)i * 64 + u * 8 + 4) = v1;

  psum[u * 32 + p] = s;
  __syncthreads();
  if (t < 32) {
    double acc = 0.0;
    #pragma unroll
    for (int uu = 0; uu < 8; ++uu) acc += psum[uu * 32 + t];
    sq[blockIdx.x * 32 + t] = (float)(0.5 * acc);   // HALF |x|^2
  }
}

// ---------- two-pass hi-only MFMA distance + theta-filter, depth-3 async pipeline ----------
// 1024 blocks x 256 threads; XCD-partitioned mapping (orig&7 -> (b,seg,row-parity)).
// Block = 32 rows x 4096 cols (64 tiles of 64 cols). Wave w owns cols w*16..+15 of each tile
// and stages exactly those -> no cross-wave LDS dependency -> no hot-loop barriers.
// QUAD-buffered: stage tile t+3 each iter, hand-counted vmcnt(9) (3 slots x 3 vmem ops
// in flight) -> ~600+ cycles of prefetch distance. Tail wraps stage index (&63).
__global__ __launch_bounds__(256, 4)
void knn_kernel(const ushort* __restrict__ phl, const float* __restrict__ sq,
                ushort* __restrict__ cand) {
  __shared__ ushort Bt[4][64 * 64];   // 32 KB quad buffer (aliased KT/KT2 in theta phase)
  __shared__ float TH[32];
  __shared__ int CNT[32];
  __shared__ ushort QU[32][QCAP];

  int t = threadIdx.x;
  int lane = t & 63;
  int w = t >> 6;
  int orig = blockIdx.x;
  int x8 = orig & 7;
  int b = x8 >> 2;
  int seg = (x8 >> 1) & 1;
  int row0 = ((orig >> 3) * 2 + (x8 & 1)) * 32;
  const ushort* pb = phl + (size_t)b * NPTS * 64;
  const float* sqb = sq + b * NPTS;

  int c15 = lane & 15, l4 = lane >> 4;
  int sw8 = c15 & 7;
  int so0 = (l4 ^ sw8) * 8;          // kk=0 slot offset (ushorts)
  int so1 = ((4 + l4) ^ sw8) * 8;    // kk=1
  int colbase = seg * 4096;
  int lp = w * 16 + c15;             // tile-local col owned by this lane
  const float* sqp = sqb + colbase + lp;

  // A fragments [kk][rg], rows row0 + rg*16 + c15, sign-flipped (exact)
  short8 a[2][2];
  #pragma unroll
  for (int rg = 0; rg < 2; ++rg) {
    int n = row0 + rg * 16 + c15;
    const ushort* pr = pb + (size_t)n * 64;
    #pragma unroll
    for (int kk = 0; kk < 2; ++kk) {
      int slot = (kk * 4 + l4) ^ (n & 7);
      short8 v = *(const short8*)(pr + slot * 8);
      uint4v uv = *(uint4v*)&v;
      uv ^= 0x80008000u;
      a[kk][rg] = *(short8*)&uv;
    }
  }

  // wave w stages its own 16 points (2 KB) of the tile: 2 x gload16
#define STAGE(BUF, TILE) do { \
    const ushort* src_ = pb + (size_t)(colbase + (TILE) * 64 + w * 16 + (lane >> 3)) * 64 + (lane & 7) * 8; \
    ushort* dst_ = &Bt[BUF][w * 16 * 64]; \
    gload16(src_, dst_); \
    gload16(src_ + 512, dst_ + 512); \
  } while (0)

#define COMPKEYS(BUF, SQV, C0, C1) \
    const ushort* bt_ = &Bt[BUF][lp * 64]; \
    short8 b0 = *(const short8*)(bt_ + so0); \
    short8 b1 = *(const short8*)(bt_ + so1); \
    f32x4 C0 = {SQV, SQV, SQV, SQV}, C1 = C0; \
    C0 = MFMA16(a[0][0], b0, C0); C1 = MFMA16(a[0][1], b0, C1); \
    C0 = MFMA16(a[1][0], b1, C0); C1 = MFMA16(a[1][1], b1, C1);

#define VMW9 asm volatile("s_waitcnt vmcnt(9)" ::: "memory")

  // ================= PASS A: per-lane top-2 per owned row =================
  float k1[2][4], k2[2][4];
  #pragma unroll
  for (int rg = 0; rg < 2; ++rg)
    #pragma unroll
    for (int r = 0; r < 4; ++r) { k1[rg][r] = __builtin_inff(); k2[rg][r] = __builtin_inff(); }

#define SELA(C0, C1) { \
    _Pragma("unroll") \
    for (int r = 0; r < 4; ++r) { \
      k2[0][r] = __builtin_amdgcn_fmed3f(C0[r], k1[0][r], k2[0][r]); \
      k1[0][r] = fminf(C0[r], k1[0][r]); \
      k2[1][r] = __builtin_amdgcn_fmed3f(C1[r], k1[1][r], k2[1][r]); \
      k1[1][r] = fminf(C1[r], k1[1][r]); \
    } }

  {
    asm volatile("s_waitcnt vmcnt(0)" ::: "memory");
    STAGE(0, 0); float sqA = sqp[0];
    STAGE(1, 1); float sqB = sqp[64];
    STAGE(2, 2); float sqC = sqp[128];
    float sqD;
    for (int g = 0; g < 16; ++g) {
      int t4 = g * 4;
      STAGE(3, (t4 + 3) & 63); sqD = sqp[((t4 + 3) & 63) * 64];
      VMW9; { COMPKEYS(0, sqA, c0, c1); SELA(c0, c1); }
      STAGE(0, (t4 + 4) & 63); sqA = sqp[((t4 + 4) & 63) * 64];
      VMW9; { COMPKEYS(1, sqB, c0, c1); SELA(c0, c1); }
      STAGE(1, (t4 + 5) & 63); sqB = sqp[((t4 + 5) & 63) * 64];
      VMW9; { COMPKEYS(2, sqC, c0, c1); SELA(c0, c1); }
      STAGE(2, (t4 + 6) & 63); sqC = sqp[((t4 + 6) & 63) * 64];
      VMW9; { COMPKEYS(3, sqD, c0, c1); SELA(c0, c1); }
    }
  }

  // ================= subset: KT[32][128] -> pair-merge KT2[32][64] (alias quad-buf) =================
  __syncthreads();   // drains vmcnt -> in-flight wrapped stages land before KT overwrites Bt
  float* KT = (float*)&Bt[0][0];    // 16 KB (buffers 0..1)
  float* KT2 = (float*)&Bt[2][0];   // 8 KB (buffer 2)
  #pragma unroll
  for (int rg = 0; rg < 2; ++rg)
    #pragma unroll
    for (int r = 0; r < 4; ++r) {
      int row = rg * 16 + l4 * 4 + r;
      KT[row * 128 + (w * 16 + c15) * 2] = k1[rg][r];
      KT[row * 128 + (w * 16 + c15) * 2 + 1] = k2[rg][r];
    }
  __syncthreads();
  #pragma unroll
  for (int it = 0; it < 4; ++it) {
    int idx = t + it * 256;               // 0..1023
    int row = idx >> 5, j = idx & 31;
    float a1 = KT[row * 128 + j * 2], a2 = KT[row * 128 + j * 2 + 1];
    float b1 = KT[row * 128 + 64 + j * 2], b2 = KT[row * 128 + 64 + j * 2 + 1];
    KT2[row * 64 + j * 2] = fminf(a1, b1);
    KT2[row * 64 + j * 2 + 1] = fminf(fmaxf(a1, b1), fminf(a2, b2));
  }
  __syncthreads();

  // ================= theta per row = 22nd smallest of 64-subset (+slack) =================
  {
    int row = t >> 3;
    int j0 = (t & 7) * 8;
    const f32x4* vr4 = (const f32x4*)(KT2 + row * 64);
    float vj[8];
    *(f32x4*)vj = vr4[(t & 7) * 2];
    *(f32x4*)(vj + 4) = vr4[(t & 7) * 2 + 1];
    int rank[8];
    #pragma unroll
    for (int jj = 0; jj < 8; ++jj) rank[jj] = 0;
    for (int m4 = 0; m4 < 16; ++m4) {
      f32x4 vm = vr4[m4];
      #pragma unroll
      for (int e = 0; e < 4; ++e) {
        int m = m4 * 4 + e;
        float ve = vm[e];
        #pragma unroll
        for (int jj = 0; jj < 8; ++jj)
          rank[jj] += (ve < vj[jj] || (ve == vj[jj] && m < j0 + jj)) ? 1 : 0;
      }
    }
    #pragma unroll
    for (int jj = 0; jj < 8; ++jj)
      if (rank[jj] == THRANK) TH[row] = vj[jj];
    if (t < 32) CNT[t] = 0;
  }
  __syncthreads();
  float th0[4], th1[4];
  #pragma unroll
  for (int r = 0; r < 4; ++r) {
    th0[r] = TH[l4 * 4 + r] + THSLACK;
    th1[r] = TH[16 + l4 * 4 + r] + THSLACK;
  }

  // ================= PASS B: recompute (bitwise identical) + collect key<=theta =================
#define SELB(C0, C1, GCOL) { \
    _Pragma("unroll") \
    for (int r = 0; r < 4; ++r) { \
      if (C0[r] <= th0[r]) { \
        int rw = l4 * 4 + r; \
        int pos = atomicAdd(&CNT[rw], 1); \
        if (pos < QCAP) QU[rw][pos] = (ushort)(GCOL); \
      } \
      if (C1[r] <= th1[r]) { \
        int rw = 16 + l4 * 4 + r; \
        int pos = atomicAdd(&CNT[rw], 1); \
        if (pos < QCAP) QU[rw][pos] = (ushort)(GCOL); \
      } \
    } }

  {
    asm volatile("s_waitcnt vmcnt(0)" ::: "memory");
    STAGE(0, 0); float sqA = sqp[0];
    STAGE(1, 1); float sqB = sqp[64];
    STAGE(2, 2); float sqC = sqp[128];
    float sqD;
    for (int g = 0; g < 16; ++g) {
      int t4 = g * 4;
      int gc = colbase + t4 * 64 + lp;
      STAGE(3, (t4 + 3) & 63); sqD = sqp[((t4 + 3) & 63) * 64];
      VMW9; { COMPKEYS(0, sqA, c0, c1); SELB(c0, c1, gc); }
      STAGE(0, (t4 + 4) & 63); sqA = sqp[((t4 + 4) & 63) * 64];
      VMW9; { COMPKEYS(1, sqB, c0, c1); SELB(c0, c1, gc + 64); }
      STAGE(1, (t4 + 5) & 63); sqB = sqp[((t4 + 5) & 63) * 64];
      VMW9; { COMPKEYS(2, sqC, c0, c1); SELB(c0, c1, gc + 128); }
      STAGE(2, (t4 + 6) & 63); sqC = sqp[((t4 + 6) & 63) * 64];
      VMW9; { COMPKEYS(3, sqD, c0, c1); SELB(c0, c1, gc + 192); }
    }
  }

  // ================= pad + dump queues =================
  __syncthreads();
  for (int i = t; i < 32 * QCAP; i += 256) {
    int row = i / QCAP, s2 = i % QCAP;
    int c2 = CNT[row]; if (c2 > QCAP) c2 = QCAP;
    ushort v = (s2 < c2) ? QU[row][s2] : (ushort)0xFFFFu;
    cand[((size_t)(b * NPTS + row0 + row) * 2 + seg) * QCAP + s2] = v;
  }
}

// ---------- exact f64 re-rank of up to 80 candidates, wave per point ----------
__global__ void refine_kernel(const float* __restrict__ pct, const ushort* __restrict__ cand,
                              int* __restrict__ knn, float* __restrict__ idxf) {
  int gw = (blockIdx.x * 256 + threadIdx.x) >> 6;  // 0..16383
  int lane = threadIdx.x & 63;
  int b = gw >> 13, n = gw & (NPTS - 1);
  const float* pcb = pct + (size_t)b * NPTS * 64;
  const ushort* cb = cand + (size_t)gw * (2 * QCAP);
  const float* qp = pcb + (size_t)n * 64;

  unsigned ciA = cb[lane];
  unsigned ciB = (lane < 2 * QCAP - 64) ? (unsigned)cb[64 + lane] : 0xFFFFu;
  double dA = __builtin_inf(), dB = __builtin_inf();
  if (ciA != 0xFFFFu) {
    const float* cp = pcb + (size_t)ciA * 64;
    double s = 0.0;
    #pragma unroll
    for (int u = 0; u < 16; ++u) {
      f32x4 cv = *(const f32x4*)(cp + u * 4);
      f32x4 qv = *(const f32x4*)(qp + u * 4);
      #pragma unroll
      for (int e = 0; e < 4; ++e) {
        double diff = (double)cv[e] - (double)qv[e];
        s = fma(diff, diff, s);
      }
    }
    dA = s;
  }
  if (ciB != 0xFFFFu) {
    const float* cp = pcb + (size_t)ciB * 64;
    double s = 0.0;
    #pragma unroll
    for (int u = 0; u < 16; ++u) {
      f32x4 cv = *(const f32x4*)(cp + u * 4);
      f32x4 qv = *(const f32x4*)(qp + u * 4);
      #pragma unroll
      for (int e = 0; e < 4; ++e) {
        double diff = (double)cv[e] - (double)qv[e];
        s = fma(diff, diff, s);
      }
    }
    dB = s;
  }

  int rA = 0, rB = 0;
  for (int j = 0; j < 64; ++j) {
    double dk = __shfl(dA, j);
    unsigned ik = (unsigned)__shfl((int)ciA, j);
    rA += ((dk < dA) || (dk == dA && ik < ciA)) ? 1 : 0;
    rB += ((dk < dB) || (dk == dB && ik < ciB)) ? 1 : 0;
  }
  for (int j = 0; j < 2 * QCAP - 64; ++j) {
    double dk = __shfl(dB, j);
    unsigned ik = (unsigned)__shfl((int)ciB, j);
    rA += ((dk < dA) || (dk == dA && ik < ciA)) ? 1 : 0;
    rB += ((dk < dB) || (dk == dB && ik < ciB)) ? 1 : 0;
  }
  if (ciA != 0xFFFFu && rA < KOUT) {
    size_t o = ((size_t)b * KOUT + rA) * NPTS + n;
    knn[o] = (int)ciA;
    idxf[o] = (float)ciA;
  }
  if (lane < 2 * QCAP - 64 && ciB != 0xFFFFu && rB < KOUT) {
    size_t o = ((size_t)b * KOUT + rB) * NPTS + n;
    knn[o] = (int)ciB;
    idxf[o] = (float)ciB;
  }
}

// ---------- edge features: out [B][128][17][N]; thread handles 4 n-values (float4) ----------
__global__ __launch_bounds__(256)
void edge_kernel(const float* __restrict__ pc, const int* __restrict__ knn,
                 float* __restrict__ out) {
  int n = (blockIdx.x * 256 + threadIdx.x) * 4;
  int z = blockIdx.y;
  int b = z >> 6, c = z & 63;
  const float* row = pc + ((size_t)b * DIM + c) * NPTS;
  f32x4 central = *(const f32x4*)(row + n);
  size_t base = (((size_t)b * 2 * DIM + c) * KOUT) * NPTS + n;
  const int* kb = knn + (size_t)b * KOUT * NPTS + n;
  #pragma unroll
  for (int k = 0; k < KOUT; ++k) {
    int4 nb = *(const int4*)(kb + (size_t)k * NPTS);
    f32x4 nv = {row[nb.x], row[nb.y], row[nb.z], row[nb.w]};
    *(f32x4*)(out + base + (size_t)k * NPTS) = central;
    *(f32x4*)(out + base + (size_t)(DIM * KOUT + k) * NPTS) = nv - central;
  }
}

extern "C" void kernel_launch(void* const* d_in, const int* in_sizes, int n_in,
                              void* d_out, int out_size, void* d_ws, size_t ws_size,
                              hipStream_t stream) {
  const float* pc = (const float*)d_in[0];
  float* out = (float*)d_out;
  char* ws = (char*)d_ws;
  ushort* phl = (ushort*)ws;                                     // 2 MB (hi only)
  float* pct  = (float*)(ws + (size_t)2 * 1024 * 1024);          // 4 MB
  float* sq   = (float*)(ws + (size_t)6 * 1024 * 1024);          // 64 KB
  ushort* cand = (ushort*)(ws + (size_t)6 * 1024 * 1024 + 65536);
  int* knn    = (int*)(ws + (size_t)6 * 1024 * 1024 + 65536 + (size_t)16384 * 2 * QCAP * 2);

  float* idxf = out + (size_t)BATCH * 2 * DIM * KOUT * NPTS;

  prep_kernel<<<512, 256, 0, stream>>>(pc, phl, pct, sq);
  knn_kernel<<<1024, 256, 0, stream>>>(phl, sq, cand);
  refine_kernel<<<4096, 256, 0, stream>>>(pct, cand, knn, idxf);
  edge_kernel<<<dim3(NPTS / 1024, BATCH * DIM), 256, 0, stream>>>(pc, knn, out);
}

// Round 15
// 191.684 us; speedup vs baseline: 1.4701x; 1.0293x over previous
//
#include <hip/hip_runtime.h>

#define NPTS 8192
#define DIM 64
#define BATCH 2
#define KOUT 17
#define QCAP 40     // queue capacity per (row, seg)
#define THRANK 21   // theta = 22nd smallest of the 64-subset
#define THSLACK 0.25f

typedef float f32x4 __attribute__((ext_vector_type(4)));
typedef short short8 __attribute__((ext_vector_type(8)));
typedef unsigned int uint4v __attribute__((ext_vector_type(4)));

#define MFMA16(A, B, C) __builtin_amdgcn_mfma_f32_16x16x32_bf16(A, B, C, 0, 0, 0)

__device__ __forceinline__ void gload16(const void* g, void* lds) {
  __builtin_amdgcn_global_load_lds((const __attribute__((address_space(1))) void*)g,
                                   (__attribute__((address_space(3))) void*)lds, 16, 0, 0);
}

// ---------- prep: permuted hi bf16 (ph), contiguous f32 (pct), 0.5*|x|^2 ----------
__global__ __launch_bounds__(256)
void prep_kernel(const float* __restrict__ pc, ushort* __restrict__ phl,
                 float* __restrict__ pct, float* __restrict__ sq) {
  __shared__ double psum[256];
  int t = threadIdx.x;
  int u = t >> 5;           // 0..7  (dims u*8 .. u*8+7)
  int p = t & 31;           // 0..31 (point within block)
  int i = blockIdx.x * 32 + p;   // 0..16383
  int b = i >> 13, n = i & (NPTS - 1);
  const float* g = pc + (size_t)b * DIM * NPTS + n;

  float x[8];
  short8 hv;
  double s = 0.0;
  #pragma unroll
  for (int e = 0; e < 8; ++e) {
    x[e] = g[(size_t)(u * 8 + e) * NPTS];
    s += (double)x[e] * (double)x[e];
    unsigned uu = __float_as_uint(x[e]);
    unsigned r = uu + (0x7fffu + ((uu >> 16) & 1));
    hv[e] = (short)((r >> 16) & 0xffffu);   // bf16 RNE
  }
  int slot = u ^ (n & 7);
  *(short8*)(phl + (size_t)i * 64 + slot * 8) = hv;
  f32x4 v0 = {x[0], x[1], x[2], x[3]}, v1 = {x[4], x[5], x[6], x[7]};
  *(f32x4*)(pct + (size_t)i * 64 + u * 8) = v0;
  *(f32x4*)(pct + (size_t)i * 64 + u * 8 + 4) = v1;

  psum[u * 32 + p] = s;
  __syncthreads();
  if (t < 32) {
    double acc = 0.0;
    #pragma unroll
    for (int uu = 0; uu < 8; ++uu) acc += psum[uu * 32 + t];
    sq[blockIdx.x * 32 + t] = (float)(0.5 * acc);   // HALF |x|^2
  }
}

// ---------- two-pass hi-only MFMA distance + theta-filter, wide-wave async pipeline ----------
// 1024 blocks x 256 threads; XCD-partitioned mapping (orig&7 -> (b,seg,row-parity)).
// Block = 32 rows x 4096 cols, tiles of 128 cols (32 tiles/pass). Wave w owns cols
// w*32..w*32+31 (TWO 16-col groups sharing A-frags + staged tile) and stages exactly
// those -> no cross-wave LDS dependency -> no hot-loop barriers. Dual-buffered,
// hand-counted vmcnt(6) (4 gload + 2 sq in flight). 1024 keys per wave-iter.
__global__ __launch_bounds__(256, 4)
void knn_kernel(const ushort* __restrict__ phl, const float* __restrict__ sq,
                ushort* __restrict__ cand) {
  __shared__ ushort Bt[2][128 * 64];   // 2 x 16 KB dual buffer (aliased KT/KT2 in theta phase)
  __shared__ float TH[32];
  __shared__ int CNT[32];
  __shared__ ushort QU[32][QCAP];

  int t = threadIdx.x;
  int lane = t & 63;
  int w = t >> 6;
  int orig = blockIdx.x;
  int x8 = orig & 7;
  int b = x8 >> 2;
  int seg = (x8 >> 1) & 1;
  int row0 = ((orig >> 3) * 2 + (x8 & 1)) * 32;
  const ushort* pb = phl + (size_t)b * NPTS * 64;
  const float* sqb = sq + b * NPTS;

  int c15 = lane & 15, l4 = lane >> 4;
  int sw8 = c15 & 7;
  int so0 = (l4 ^ sw8) * 8;          // kk=0 slot offset (ushorts)
  int so1 = ((4 + l4) ^ sw8) * 8;    // kk=1
  int colbase = seg * 4096;
  const float* sqp0 = sqb + colbase + w * 32 + c15;        // col-group 0
  const float* sqp1 = sqp0 + 16;                            // col-group 1

  // A fragments [kk][rg], rows row0 + rg*16 + c15, sign-flipped (exact)
  short8 a[2][2];
  #pragma unroll
  for (int rg = 0; rg < 2; ++rg) {
    int n = row0 + rg * 16 + c15;
    const ushort* pr = pb + (size_t)n * 64;
    #pragma unroll
    for (int kk = 0; kk < 2; ++kk) {
      int slot = (kk * 4 + l4) ^ (n & 7);
      short8 v = *(const short8*)(pr + slot * 8);
      uint4v uv = *(uint4v*)&v;
      uv ^= 0x80008000u;
      a[kk][rg] = *(short8*)&uv;
    }
  }

  // wave w stages its own 32 points (4 KB) of the tile: 4 x gload16
#define STAGE(BUF, TILE) do { \
    const ushort* src_ = pb + (size_t)(colbase + (TILE) * 128 + w * 32 + (lane >> 3)) * 64 + (lane & 7) * 8; \
    ushort* dst_ = &Bt[BUF][w * 32 * 64]; \
    gload16(src_,         dst_); \
    gload16(src_ + 512,   dst_ + 512); \
    gload16(src_ + 1024,  dst_ + 1024); \
    gload16(src_ + 1536,  dst_ + 1536); \
  } while (0)

// compute 16 keys/lane: col-groups A(=cg0)/B(=cg1) x row-groups 0/1
#define COMPALL(BUF, S0, S1) \
    const ushort* btA_ = &Bt[BUF][(w * 32 + c15) * 64]; \
    const ushort* btB_ = btA_ + 16 * 64; \
    short8 p0_ = *(const short8*)(btA_ + so0); \
    short8 p1_ = *(const short8*)(btA_ + so1); \
    short8 q0_ = *(const short8*)(btB_ + so0); \
    short8 q1_ = *(const short8*)(btB_ + so1); \
    f32x4 cA0 = {S0, S0, S0, S0}, cA1 = cA0; \
    f32x4 cB0 = {S1, S1, S1, S1}, cB1 = cB0; \
    cA0 = MFMA16(a[0][0], p0_, cA0); cA1 = MFMA16(a[0][1], p0_, cA1); \
    cB0 = MFMA16(a[0][0], q0_, cB0); cB1 = MFMA16(a[0][1], q0_, cB1); \
    cA0 = MFMA16(a[1][0], p1_, cA0); cA1 = MFMA16(a[1][1], p1_, cA1); \
    cB0 = MFMA16(a[1][0], q1_, cB0); cB1 = MFMA16(a[1][1], q1_, cB1);

#define VMW6 asm volatile("s_waitcnt vmcnt(6)" ::: "memory")
#define VMW0 asm volatile("s_waitcnt vmcnt(0)" ::: "memory")

  // ================= PASS A: per-lane top-2 per (rowgroup, colgroup, r) =================
  float k1[2][2][4], k2[2][2][4];   // [rg][cg][r]
  #pragma unroll
  for (int rg = 0; rg < 2; ++rg)
    #pragma unroll
    for (int cg = 0; cg < 2; ++cg)
      #pragma unroll
      for (int r = 0; r < 4; ++r) { k1[rg][cg][r] = __builtin_inff(); k2[rg][cg][r] = __builtin_inff(); }

#define SELA(BUF, S0, S1) { \
    COMPALL(BUF, S0, S1); \
    _Pragma("unroll") \
    for (int r = 0; r < 4; ++r) { \
      k2[0][0][r] = __builtin_amdgcn_fmed3f(cA0[r], k1[0][0][r], k2[0][0][r]); \
      k1[0][0][r] = fminf(cA0[r], k1[0][0][r]); \
      k2[1][0][r] = __builtin_amdgcn_fmed3f(cA1[r], k1[1][0][r], k2[1][0][r]); \
      k1[1][0][r] = fminf(cA1[r], k1[1][0][r]); \
      k2[0][1][r] = __builtin_amdgcn_fmed3f(cB0[r], k1[0][1][r], k2[0][1][r]); \
      k1[0][1][r] = fminf(cB0[r], k1[0][1][r]); \
      k2[1][1][r] = __builtin_amdgcn_fmed3f(cB1[r], k1[1][1][r], k2[1][1][r]); \
      k1[1][1][r] = fminf(cB1[r], k1[1][1][r]); \
    } }

  {
    VMW0;
    STAGE(0, 0); float s0A = sqp0[0], s1A = sqp1[0];
    float s0B, s1B;
    for (int tt = 0; tt < 30; tt += 2) {
      STAGE(1, tt + 1); s0B = sqp0[(tt + 1) * 128]; s1B = sqp1[(tt + 1) * 128];
      VMW6; { SELA(0, s0A, s1A); }
      STAGE(0, tt + 2); s0A = sqp0[(tt + 2) * 128]; s1A = sqp1[(tt + 2) * 128];
      VMW6; { SELA(1, s0B, s1B); }
    }
    STAGE(1, 31); s0B = sqp0[31 * 128]; s1B = sqp1[31 * 128];
    VMW6; { SELA(0, s0A, s1A); }
    VMW0; { SELA(1, s0B, s1B); }
  }

  // ============ in-register colgroup merge (top-2 of 4) -> KT[32][128] ============
  __syncthreads();
  float* KT = (float*)&Bt[0][0];    // 16 KB (buffer 0)
  float* KT2 = (float*)&Bt[1][0];   // 8 KB (buffer 1 start)
  #pragma unroll
  for (int rg = 0; rg < 2; ++rg)
    #pragma unroll
    for (int r = 0; r < 4; ++r) {
      float x1 = k1[rg][0][r], x2 = k2[rg][0][r];
      float y1 = k1[rg][1][r], y2 = k2[rg][1][r];
      float m1 = fminf(x1, y1);
      float m2 = fminf(fmaxf(x1, y1), fminf(x2, y2));
      int row = rg * 16 + l4 * 4 + r;
      KT[row * 128 + (w * 16 + c15) * 2] = m1;
      KT[row * 128 + (w * 16 + c15) * 2 + 1] = m2;
    }
  __syncthreads();
  #pragma unroll
  for (int it = 0; it < 4; ++it) {
    int idx = t + it * 256;               // 0..1023
    int row = idx >> 5, j = idx & 31;
    float a1 = KT[row * 128 + j * 2], a2 = KT[row * 128 + j * 2 + 1];
    float b1 = KT[row * 128 + 64 + j * 2], b2 = KT[row * 128 + 64 + j * 2 + 1];
    KT2[row * 64 + j * 2] = fminf(a1, b1);
    KT2[row * 64 + j * 2 + 1] = fminf(fmaxf(a1, b1), fminf(a2, b2));
  }
  __syncthreads();

  // ================= theta per row = 22nd smallest of 64-subset (+slack) =================
  {
    int row = t >> 3;
    int j0 = (t & 7) * 8;
    const f32x4* vr4 = (const f32x4*)(KT2 + row * 64);
    float vj[8];
    *(f32x4*)vj = vr4[(t & 7) * 2];
    *(f32x4*)(vj + 4) = vr4[(t & 7) * 2 + 1];
    int rank[8];
    #pragma unroll
    for (int jj = 0; jj < 8; ++jj) rank[jj] = 0;
    for (int m4 = 0; m4 < 16; ++m4) {
      f32x4 vm = vr4[m4];
      #pragma unroll
      for (int e = 0; e < 4; ++e) {
        int m = m4 * 4 + e;
        float ve = vm[e];
        #pragma unroll
        for (int jj = 0; jj < 8; ++jj)
          rank[jj] += (ve < vj[jj] || (ve == vj[jj] && m < j0 + jj)) ? 1 : 0;
      }
    }
    #pragma unroll
    for (int jj = 0; jj < 8; ++jj)
      if (rank[jj] == THRANK) TH[row] = vj[jj];
    if (t < 32) CNT[t] = 0;
  }
  __syncthreads();
  float th0[4], th1[4];
  #pragma unroll
  for (int r = 0; r < 4; ++r) {
    th0[r] = TH[l4 * 4 + r] + THSLACK;
    th1[r] = TH[16 + l4 * 4 + r] + THSLACK;
  }

  // ================= PASS B: recompute (bitwise identical) + collect key<=theta =================
#define SELB(BUF, S0, S1, GC0) { \
    COMPALL(BUF, S0, S1); \
    int gc1_ = (GC0) + 16; \
    _Pragma("unroll") \
    for (int r = 0; r < 4; ++r) { \
      if (cA0[r] <= th0[r]) { \
        int rw = l4 * 4 + r; \
        int pos = atomicAdd(&CNT[rw], 1); \
        if (pos < QCAP) QU[rw][pos] = (ushort)(GC0); \
      } \
      if (cA1[r] <= th1[r]) { \
        int rw = 16 + l4 * 4 + r; \
        int pos = atomicAdd(&CNT[rw], 1); \
        if (pos < QCAP) QU[rw][pos] = (ushort)(GC0); \
      } \
      if (cB0[r] <= th0[r]) { \
        int rw = l4 * 4 + r; \
        int pos = atomicAdd(&CNT[rw], 1); \
        if (pos < QCAP) QU[rw][pos] = (ushort)gc1_; \
      } \
      if (cB1[r] <= th1[r]) { \
        int rw = 16 + l4 * 4 + r; \
        int pos = atomicAdd(&CNT[rw], 1); \
        if (pos < QCAP) QU[rw][pos] = (ushort)gc1_; \
      } \
    } }

  {
    VMW0;
    STAGE(0, 0); float s0A = sqp0[0], s1A = sqp1[0];
    float s0B, s1B;
    int gcA = colbase + w * 32 + c15;
    for (int tt = 0; tt < 30; tt += 2) {
      STAGE(1, tt + 1); s0B = sqp0[(tt + 1) * 128]; s1B = sqp1[(tt + 1) * 128];
      VMW6; { SELB(0, s0A, s1A, gcA); }
      STAGE(0, tt + 2); s0A = sqp0[(tt + 2) * 128]; s1A = sqp1[(tt + 2) * 128];
      VMW6; { SELB(1, s0B, s1B, gcA + 128); }
      gcA += 256;
    }
    STAGE(1, 31); s0B = sqp0[31 * 128]; s1B = sqp1[31 * 128];
    VMW6; { SELB(0, s0A, s1A, gcA); }
    VMW0; { SELB(1, s0B, s1B, gcA + 128); }
  }

  // ================= pad + dump queues =================
  __syncthreads();
  for (int i = t; i < 32 * QCAP; i += 256) {
    int row = i / QCAP, s2 = i % QCAP;
    int c2 = CNT[row]; if (c2 > QCAP) c2 = QCAP;
    ushort v = (s2 < c2) ? QU[row][s2] : (ushort)0xFFFFu;
    cand[((size_t)(b * NPTS + row0 + row) * 2 + seg) * QCAP + s2] = v;
  }
}

// ---------- exact f64 re-rank of up to 80 candidates, wave per point ----------
__global__ void refine_kernel(const float* __restrict__ pct, const ushort* __restrict__ cand,
                              int* __restrict__ knn, float* __restrict__ idxf) {
  int gw = (blockIdx.x * 256 + threadIdx.x) >> 6;  // 0..16383
  int lane = threadIdx.x & 63;
  int b = gw >> 13, n = gw & (NPTS - 1);
  const float* pcb = pct + (size_t)b * NPTS * 64;
  const ushort* cb = cand + (size_t)gw * (2 * QCAP);
  const float* qp = pcb + (size_t)n * 64;

  unsigned ciA = cb[lane];
  unsigned ciB = (lane < 2 * QCAP - 64) ? (unsigned)cb[64 + lane] : 0xFFFFu;
  double dA = __builtin_inf(), dB = __builtin_inf();
  if (ciA != 0xFFFFu) {
    const float* cp = pcb + (size_t)ciA * 64;
    double s = 0.0;
    #pragma unroll
    for (int u = 0; u < 16; ++u) {
      f32x4 cv = *(const f32x4*)(cp + u * 4);
      f32x4 qv = *(const f32x4*)(qp + u * 4);
      #pragma unroll
      for (int e = 0; e < 4; ++e) {
        double diff = (double)cv[e] - (double)qv[e];
        s = fma(diff, diff, s);
      }
    }
    dA = s;
  }
  if (ciB != 0xFFFFu) {
    const float* cp = pcb + (size_t)ciB * 64;
    double s = 0.0;
    #pragma unroll
    for (int u = 0; u < 16; ++u) {
      f32x4 cv = *(const f32x4*)(cp + u * 4);
      f32x4 qv = *(const f32x4*)(qp + u * 4);
      #pragma unroll
      for (int e = 0; e < 4; ++e) {
        double diff = (double)cv[e] - (double)qv[e];
        s = fma(diff, diff, s);
      }
    }
    dB = s;
  }

  int rA = 0, rB = 0;
  for (int j = 0; j < 64; ++j) {
    double dk = __shfl(dA, j);
    unsigned ik = (unsigned)__shfl((int)ciA, j);
    rA += ((dk < dA) || (dk == dA && ik < ciA)) ? 1 : 0;
    rB += ((dk < dB) || (dk == dB && ik < ciB)) ? 1 : 0;
  }
  for (int j = 0; j < 2 * QCAP - 64; ++j) {
    double dk = __shfl(dB, j);
    unsigned ik = (unsigned)__shfl((int)ciB, j);
    rA += ((dk < dA) || (dk == dA && ik < ciA)) ? 1 : 0;
    rB += ((dk < dB) || (dk == dB && ik < ciB)) ? 1 : 0;
  }
  if (ciA != 0xFFFFu && rA < KOUT) {
    size_t o = ((size_t)b * KOUT + rA) * NPTS + n;
    knn[o] = (int)ciA;
    idxf[o] = (float)ciA;
  }
  if (lane < 2 * QCAP - 64 && ciB != 0xFFFFu && rB < KOUT) {
    size_t o = ((size_t)b * KOUT + rB) * NPTS + n;
    knn[o] = (int)ciB;
    idxf[o] = (float)ciB;
  }
}

// ---------- edge features: out [B][128][17][N]; thread handles 4 n-values (float4) ----------
__global__ __launch_bounds__(256)
void edge_kernel(const float* __restrict__ pc, const int* __restrict__ knn,
                 float* __restrict__ out) {
  int n = (blockIdx.x * 256 + threadIdx.x) * 4;
  int z = blockIdx.y;
  int b = z >> 6, c = z & 63;
  const float* row = pc + ((size_t)b * DIM + c) * NPTS;
  f32x4 central = *(const f32x4*)(row + n);
  size_t base = (((size_t)b * 2 * DIM + c) * KOUT) * NPTS + n;
  const int* kb = knn + (size_t)b * KOUT * NPTS + n;
  #pragma unroll
  for (int k = 0; k < KOUT; ++k) {
    int4 nb = *(const int4*)(kb + (size_t)k * NPTS);
    f32x4 nv = {row[nb.x], row[nb.y], row[nb.z], row[nb.w]};
    *(f32x4*)(out + base + (size_t)k * NPTS) = central;
    *(f32x4*)(out + base + (size_t)(DIM * KOUT + k) * NPTS) = nv - central;
  }
}

extern "C" void kernel_launch(void* const* d_in, const int* in_sizes, int n_in,
                              void* d_out, int out_size, void* d_ws, size_t ws_size,
                              hipStream_t stream) {
  const float* pc = (const float*)d_in[0];
  float* out = (float*)d_out;
  char* ws = (char*)d_ws;
  ushort* phl = (ushort*)ws;                                     // 2 MB (hi only)
  float* pct  = (float*)(ws + (size_t)2 * 1024 * 1024);          // 4 MB
  float* sq   = (float*)(ws + (size_t)6 * 1024 * 1024);          // 64 KB
  ushort* cand = (ushort*)(ws + (size_t)6 * 1024 * 1024 + 65536);
  int* knn    = (int*)(ws + (size_t)6 * 1024 * 1024 + 65536 + (size_t)16384 * 2 * QCAP * 2);

  float* idxf = out + (size_t)BATCH * 2 * DIM * KOUT * NPTS;

  prep_kernel<<<512, 256, 0, stream>>>(pc, phl, pct, sq);
  knn_kernel<<<1024, 256, 0, stream>>>(phl, sq, cand);
  refine_kernel<<<4096, 256, 0, stream>>>(pct, cand, knn, idxf);
  edge_kernel<<<dim3(NPTS / 1024, BATCH * DIM), 256, 0, stream>>>(pc, knn, out);
}

// Round 16
// 181.746 us; speedup vs baseline: 1.5505x; 1.0547x over previous
//
#include <hip/hip_runtime.h>

#define NPTS 8192
#define DIM 64
#define BATCH 2
#define KOUT 17
#define QCAP 40     // queue capacity per (row, seg)
#define THRANK 21   // theta = 22nd smallest of the 64-subset
#define THSLACK 0.25f

typedef float f32x4 __attribute__((ext_vector_type(4)));
typedef short short8 __attribute__((ext_vector_type(8)));
typedef unsigned int uint4v __attribute__((ext_vector_type(4)));

#define MFMA16(A, B, C) __builtin_amdgcn_mfma_f32_16x16x32_bf16(A, B, C, 0, 0, 0)

__device__ __forceinline__ void gload16(const void* g, void* lds) {
  __builtin_amdgcn_global_load_lds((const __attribute__((address_space(1))) void*)g,
                                   (__attribute__((address_space(3))) void*)lds, 16, 0, 0);
}

// ---------- prep: permuted hi bf16 (ph), contiguous f32 (pct), 0.5*|x|^2 ----------
__global__ __launch_bounds__(256)
void prep_kernel(const float* __restrict__ pc, ushort* __restrict__ phl,
                 float* __restrict__ pct, float* __restrict__ sq) {
  __shared__ double psum[256];
  int t = threadIdx.x;
  int u = t >> 5;           // 0..7  (dims u*8 .. u*8+7)
  int p = t & 31;           // 0..31 (point within block)
  int i = blockIdx.x * 32 + p;   // 0..16383
  int b = i >> 13, n = i & (NPTS - 1);
  const float* g = pc + (size_t)b * DIM * NPTS + n;

  float x[8];
  short8 hv;
  double s = 0.0;
  #pragma unroll
  for (int e = 0; e < 8; ++e) {
    x[e] = g[(size_t)(u * 8 + e) * NPTS];
    s += (double)x[e] * (double)x[e];
    unsigned uu = __float_as_uint(x[e]);
    unsigned r = uu + (0x7fffu + ((uu >> 16) & 1));
    hv[e] = (short)((r >> 16) & 0xffffu);   // bf16 RNE
  }
  int slot = u ^ (n & 7);
  *(short8*)(phl + (size_t)i * 64 + slot * 8) = hv;
  f32x4 v0 = {x[0], x[1], x[2], x[3]}, v1 = {x[4], x[5], x[6], x[7]};
  *(f32x4*)(pct + (size_t)i * 64 + u * 8) = v0;
  *(f32x4*)(pct + (size_t)i * 64 + u * 8 + 4) = v1;

  psum[u * 32 + p] = s;
  __syncthreads();
  if (t < 32) {
    double acc = 0.0;
    #pragma unroll
    for (int uu = 0; uu < 8; ++uu) acc += psum[uu * 32 + t];
    sq[blockIdx.x * 32 + t] = (float)(0.5 * acc);   // HALF |x|^2
  }
}

// ---------- two-pass hi-only MFMA distance + theta-filter, wide-wave async pipeline ----------
// (structure identical to round 15; adds ccnt output, dump writes only valid entries)
__global__ __launch_bounds__(256, 4)
void knn_kernel(const ushort* __restrict__ phl, const float* __restrict__ sq,
                ushort* __restrict__ cand, ushort* __restrict__ ccnt) {
  __shared__ ushort Bt[2][128 * 64];   // 2 x 16 KB dual buffer (aliased KT/KT2 in theta phase)
  __shared__ float TH[32];
  __shared__ int CNT[32];
  __shared__ ushort QU[32][QCAP];

  int t = threadIdx.x;
  int lane = t & 63;
  int w = t >> 6;
  int orig = blockIdx.x;
  int x8 = orig & 7;
  int b = x8 >> 2;
  int seg = (x8 >> 1) & 1;
  int row0 = ((orig >> 3) * 2 + (x8 & 1)) * 32;
  const ushort* pb = phl + (size_t)b * NPTS * 64;
  const float* sqb = sq + b * NPTS;

  int c15 = lane & 15, l4 = lane >> 4;
  int sw8 = c15 & 7;
  int so0 = (l4 ^ sw8) * 8;          // kk=0 slot offset (ushorts)
  int so1 = ((4 + l4) ^ sw8) * 8;    // kk=1
  int colbase = seg * 4096;
  const float* sqp0 = sqb + colbase + w * 32 + c15;        // col-group 0
  const float* sqp1 = sqp0 + 16;                            // col-group 1

  // A fragments [kk][rg], rows row0 + rg*16 + c15, sign-flipped (exact)
  short8 a[2][2];
  #pragma unroll
  for (int rg = 0; rg < 2; ++rg) {
    int n = row0 + rg * 16 + c15;
    const ushort* pr = pb + (size_t)n * 64;
    #pragma unroll
    for (int kk = 0; kk < 2; ++kk) {
      int slot = (kk * 4 + l4) ^ (n & 7);
      short8 v = *(const short8*)(pr + slot * 8);
      uint4v uv = *(uint4v*)&v;
      uv ^= 0x80008000u;
      a[kk][rg] = *(short8*)&uv;
    }
  }

#define STAGE(BUF, TILE) do { \
    const ushort* src_ = pb + (size_t)(colbase + (TILE) * 128 + w * 32 + (lane >> 3)) * 64 + (lane & 7) * 8; \
    ushort* dst_ = &Bt[BUF][w * 32 * 64]; \
    gload16(src_,         dst_); \
    gload16(src_ + 512,   dst_ + 512); \
    gload16(src_ + 1024,  dst_ + 1024); \
    gload16(src_ + 1536,  dst_ + 1536); \
  } while (0)

#define COMPALL(BUF, S0, S1) \
    const ushort* btA_ = &Bt[BUF][(w * 32 + c15) * 64]; \
    const ushort* btB_ = btA_ + 16 * 64; \
    short8 p0_ = *(const short8*)(btA_ + so0); \
    short8 p1_ = *(const short8*)(btA_ + so1); \
    short8 q0_ = *(const short8*)(btB_ + so0); \
    short8 q1_ = *(const short8*)(btB_ + so1); \
    f32x4 cA0 = {S0, S0, S0, S0}, cA1 = cA0; \
    f32x4 cB0 = {S1, S1, S1, S1}, cB1 = cB0; \
    cA0 = MFMA16(a[0][0], p0_, cA0); cA1 = MFMA16(a[0][1], p0_, cA1); \
    cB0 = MFMA16(a[0][0], q0_, cB0); cB1 = MFMA16(a[0][1], q0_, cB1); \
    cA0 = MFMA16(a[1][0], p1_, cA0); cA1 = MFMA16(a[1][1], p1_, cA1); \
    cB0 = MFMA16(a[1][0], q1_, cB0); cB1 = MFMA16(a[1][1], q1_, cB1);

#define VMW6 asm volatile("s_waitcnt vmcnt(6)" ::: "memory")
#define VMW0 asm volatile("s_waitcnt vmcnt(0)" ::: "memory")

  // ================= PASS A: per-lane top-2 per (rowgroup, colgroup, r) =================
  float k1[2][2][4], k2[2][2][4];   // [rg][cg][r]
  #pragma unroll
  for (int rg = 0; rg < 2; ++rg)
    #pragma unroll
    for (int cg = 0; cg < 2; ++cg)
      #pragma unroll
      for (int r = 0; r < 4; ++r) { k1[rg][cg][r] = __builtin_inff(); k2[rg][cg][r] = __builtin_inff(); }

#define SELA(BUF, S0, S1) { \
    COMPALL(BUF, S0, S1); \
    _Pragma("unroll") \
    for (int r = 0; r < 4; ++r) { \
      k2[0][0][r] = __builtin_amdgcn_fmed3f(cA0[r], k1[0][0][r], k2[0][0][r]); \
      k1[0][0][r] = fminf(cA0[r], k1[0][0][r]); \
      k2[1][0][r] = __builtin_amdgcn_fmed3f(cA1[r], k1[1][0][r], k2[1][0][r]); \
      k1[1][0][r] = fminf(cA1[r], k1[1][0][r]); \
      k2[0][1][r] = __builtin_amdgcn_fmed3f(cB0[r], k1[0][1][r], k2[0][1][r]); \
      k1[0][1][r] = fminf(cB0[r], k1[0][1][r]); \
      k2[1][1][r] = __builtin_amdgcn_fmed3f(cB1[r], k1[1][1][r], k2[1][1][r]); \
      k1[1][1][r] = fminf(cB1[r], k1[1][1][r]); \
    } }

  {
    VMW0;
    STAGE(0, 0); float s0A = sqp0[0], s1A = sqp1[0];
    float s0B, s1B;
    for (int tt = 0; tt < 30; tt += 2) {
      STAGE(1, tt + 1); s0B = sqp0[(tt + 1) * 128]; s1B = sqp1[(tt + 1) * 128];
      VMW6; { SELA(0, s0A, s1A); }
      STAGE(0, tt + 2); s0A = sqp0[(tt + 2) * 128]; s1A = sqp1[(tt + 2) * 128];
      VMW6; { SELA(1, s0B, s1B); }
    }
    STAGE(1, 31); s0B = sqp0[31 * 128]; s1B = sqp1[31 * 128];
    VMW6; { SELA(0, s0A, s1A); }
    VMW0; { SELA(1, s0B, s1B); }
  }

  // ============ in-register colgroup merge (top-2 of 4) -> KT[32][128] ============
  __syncthreads();
  float* KT = (float*)&Bt[0][0];    // 16 KB (buffer 0)
  float* KT2 = (float*)&Bt[1][0];   // 8 KB (buffer 1 start)
  #pragma unroll
  for (int rg = 0; rg < 2; ++rg)
    #pragma unroll
    for (int r = 0; r < 4; ++r) {
      float x1 = k1[rg][0][r], x2 = k2[rg][0][r];
      float y1 = k1[rg][1][r], y2 = k2[rg][1][r];
      float m1 = fminf(x1, y1);
      float m2 = fminf(fmaxf(x1, y1), fminf(x2, y2));
      int row = rg * 16 + l4 * 4 + r;
      KT[row * 128 + (w * 16 + c15) * 2] = m1;
      KT[row * 128 + (w * 16 + c15) * 2 + 1] = m2;
    }
  __syncthreads();
  #pragma unroll
  for (int it = 0; it < 4; ++it) {
    int idx = t + it * 256;               // 0..1023
    int row = idx >> 5, j = idx & 31;
    float a1 = KT[row * 128 + j * 2], a2 = KT[row * 128 + j * 2 + 1];
    float b1 = KT[row * 128 + 64 + j * 2], b2 = KT[row * 128 + 64 + j * 2 + 1];
    KT2[row * 64 + j * 2] = fminf(a1, b1);
    KT2[row * 64 + j * 2 + 1] = fminf(fmaxf(a1, b1), fminf(a2, b2));
  }
  __syncthreads();

  // ================= theta per row = 22nd smallest of 64-subset (+slack) =================
  {
    int row = t >> 3;
    int j0 = (t & 7) * 8;
    const f32x4* vr4 = (const f32x4*)(KT2 + row * 64);
    float vj[8];
    *(f32x4*)vj = vr4[(t & 7) * 2];
    *(f32x4*)(vj + 4) = vr4[(t & 7) * 2 + 1];
    int rank[8];
    #pragma unroll
    for (int jj = 0; jj < 8; ++jj) rank[jj] = 0;
    for (int m4 = 0; m4 < 16; ++m4) {
      f32x4 vm = vr4[m4];
      #pragma unroll
      for (int e = 0; e < 4; ++e) {
        int m = m4 * 4 + e;
        float ve = vm[e];
        #pragma unroll
        for (int jj = 0; jj < 8; ++jj)
          rank[jj] += (ve < vj[jj] || (ve == vj[jj] && m < j0 + jj)) ? 1 : 0;
      }
    }
    #pragma unroll
    for (int jj = 0; jj < 8; ++jj)
      if (rank[jj] == THRANK) TH[row] = vj[jj];
    if (t < 32) CNT[t] = 0;
  }
  __syncthreads();
  float th0[4], th1[4];
  #pragma unroll
  for (int r = 0; r < 4; ++r) {
    th0[r] = TH[l4 * 4 + r] + THSLACK;
    th1[r] = TH[16 + l4 * 4 + r] + THSLACK;
  }

  // ================= PASS B: recompute (bitwise identical) + collect key<=theta =================
#define SELB(BUF, S0, S1, GC0) { \
    COMPALL(BUF, S0, S1); \
    int gc1_ = (GC0) + 16; \
    _Pragma("unroll") \
    for (int r = 0; r < 4; ++r) { \
      if (cA0[r] <= th0[r]) { \
        int rw = l4 * 4 + r; \
        int pos = atomicAdd(&CNT[rw], 1); \
        if (pos < QCAP) QU[rw][pos] = (ushort)(GC0); \
      } \
      if (cA1[r] <= th1[r]) { \
        int rw = 16 + l4 * 4 + r; \
        int pos = atomicAdd(&CNT[rw], 1); \
        if (pos < QCAP) QU[rw][pos] = (ushort)(GC0); \
      } \
      if (cB0[r] <= th0[r]) { \
        int rw = l4 * 4 + r; \
        int pos = atomicAdd(&CNT[rw], 1); \
        if (pos < QCAP) QU[rw][pos] = (ushort)gc1_; \
      } \
      if (cB1[r] <= th1[r]) { \
        int rw = 16 + l4 * 4 + r; \
        int pos = atomicAdd(&CNT[rw], 1); \
        if (pos < QCAP) QU[rw][pos] = (ushort)gc1_; \
      } \
    } }

  {
    VMW0;
    STAGE(0, 0); float s0A = sqp0[0], s1A = sqp1[0];
    float s0B, s1B;
    int gcA = colbase + w * 32 + c15;
    for (int tt = 0; tt < 30; tt += 2) {
      STAGE(1, tt + 1); s0B = sqp0[(tt + 1) * 128]; s1B = sqp1[(tt + 1) * 128];
      VMW6; { SELB(0, s0A, s1A, gcA); }
      STAGE(0, tt + 2); s0A = sqp0[(tt + 2) * 128]; s1A = sqp1[(tt + 2) * 128];
      VMW6; { SELB(1, s0B, s1B, gcA + 128); }
      gcA += 256;
    }
    STAGE(1, 31); s0B = sqp0[31 * 128]; s1B = sqp1[31 * 128];
    VMW6; { SELB(0, s0A, s1A, gcA); }
    VMW0; { SELB(1, s0B, s1B, gcA + 128); }
  }

  // ================= dump queues (valid entries only) + counts =================
  __syncthreads();
  int cnt_s[1];
  for (int row = w; row < 32; row += 4) {
    int c2 = CNT[row]; if (c2 > QCAP) c2 = QCAP;
    size_t base = ((size_t)(b * NPTS + row0 + row) * 2 + seg) * QCAP;
    for (int s2 = lane; s2 < c2; s2 += 64)
      cand[base + s2] = QU[row][s2];
  }
  (void)cnt_s;
  if (t < 32) {
    int c2 = CNT[t]; if (c2 > QCAP) c2 = QCAP;
    ccnt[((size_t)(b * NPTS + row0 + t) * 2 + seg)] = (ushort)c2;
  }
}

// ---------- exact f64 re-rank, count-limited, wave per point ----------
__global__ void refine_kernel(const float* __restrict__ pct, const ushort* __restrict__ cand,
                              const ushort* __restrict__ ccnt,
                              int* __restrict__ knn, float* __restrict__ idxf) {
  int gw = (blockIdx.x * 256 + threadIdx.x) >> 6;  // 0..16383
  int lane = threadIdx.x & 63;
  int b = gw >> 13, n = gw & (NPTS - 1);
  const float* pcb = pct + (size_t)b * NPTS * 64;
  const ushort* cb = cand + (size_t)gw * (2 * QCAP);
  const float* qp = pcb + (size_t)n * 64;

  int c0 = ccnt[gw * 2], c1 = ccnt[gw * 2 + 1];
  c0 = __builtin_amdgcn_readfirstlane(c0);
  c1 = __builtin_amdgcn_readfirstlane(c1);
  int tot = c0 + c1;          // >= 2*(THRANK+1) >= 44 > KOUT
  int t64 = tot < 64 ? tot : 64;
  int nB = tot - 64;          // rarely > 0

  // compacted candidates: lanes 0..tot-1
  unsigned ciA = 0xFFFFu;
  if (lane < t64) ciA = (lane < c0) ? cb[lane] : cb[QCAP + lane - c0];
  double dA = __builtin_inf();
  if (lane < t64) {
    const float* cp = pcb + (size_t)ciA * 64;
    double s = 0.0;
    #pragma unroll
    for (int u = 0; u < 16; ++u) {
      f32x4 cv = *(const f32x4*)(cp + u * 4);
      f32x4 qv = *(const f32x4*)(qp + u * 4);
      #pragma unroll
      for (int e = 0; e < 4; ++e) {
        double diff = (double)cv[e] - (double)qv[e];
        s = fma(diff, diff, s);
      }
    }
    dA = s;
  }
  unsigned ciB = 0xFFFFu;
  double dB = __builtin_inf();
  if (nB > 0) {
    if (lane < nB) {
      ciB = cb[QCAP + (lane + 64 - c0)];
      const float* cp = pcb + (size_t)ciB * 64;
      double s = 0.0;
      #pragma unroll
      for (int u = 0; u < 16; ++u) {
        f32x4 cv = *(const f32x4*)(cp + u * 4);
        f32x4 qv = *(const f32x4*)(qp + u * 4);
        #pragma unroll
        for (int e = 0; e < 4; ++e) {
          double diff = (double)cv[e] - (double)qv[e];
          s = fma(diff, diff, s);
        }
      }
      dB = s;
    }
  }

  int rA = 0, rB = 0;
  for (int j = 0; j < t64; ++j) {
    double dk = __shfl(dA, j);
    unsigned ik = (unsigned)__shfl((int)ciA, j);
    rA += ((dk < dA) || (dk == dA && ik < ciA)) ? 1 : 0;
    rB += ((dk < dB) || (dk == dB && ik < ciB)) ? 1 : 0;
  }
  if (nB > 0) {
    for (int j = 0; j < nB; ++j) {
      double dk = __shfl(dB, j);
      unsigned ik = (unsigned)__shfl((int)ciB, j);
      rA += ((dk < dA) || (dk == dA && ik < ciA)) ? 1 : 0;
      rB += ((dk < dB) || (dk == dB && ik < ciB)) ? 1 : 0;
    }
  }
  if (lane < t64 && rA < KOUT) {
    size_t o = ((size_t)b * KOUT + rA) * NPTS + n;
    knn[o] = (int)ciA;
    idxf[o] = (float)ciA;
  }
  if (nB > 0 && lane < nB && rB < KOUT) {
    size_t o = ((size_t)b * KOUT + rB) * NPTS + n;
    knn[o] = (int)ciB;
    idxf[o] = (float)ciB;
  }
}

// ---------- edge features: out [B][128][17][N]; float4 per thread, nontemporal stores ----------
__global__ __launch_bounds__(256)
void edge_kernel(const float* __restrict__ pc, const int* __restrict__ knn,
                 float* __restrict__ out) {
  int n = (blockIdx.x * 256 + threadIdx.x) * 4;
  int z = blockIdx.y;
  int b = z >> 6, c = z & 63;
  const float* row = pc + ((size_t)b * DIM + c) * NPTS;
  f32x4 central = *(const f32x4*)(row + n);
  size_t base = (((size_t)b * 2 * DIM + c) * KOUT) * NPTS + n;
  const int* kb = knn + (size_t)b * KOUT * NPTS + n;
  #pragma unroll
  for (int k = 0; k < KOUT; ++k) {
    int4 nb = *(const int4*)(kb + (size_t)k * NPTS);
    f32x4 nv = {row[nb.x], row[nb.y], row[nb.z], row[nb.w]};
    __builtin_nontemporal_store(central, (f32x4*)(out + base + (size_t)k * NPTS));
    __builtin_nontemporal_store(nv - central, (f32x4*)(out + base + (size_t)(DIM * KOUT + k) * NPTS));
  }
}

extern "C" void kernel_launch(void* const* d_in, const int* in_sizes, int n_in,
                              void* d_out, int out_size, void* d_ws, size_t ws_size,
                              hipStream_t stream) {
  const float* pc = (const float*)d_in[0];
  float* out = (float*)d_out;
  char* ws = (char*)d_ws;
  ushort* phl = (ushort*)ws;                                     // 2 MB (hi only)
  float* pct  = (float*)(ws + (size_t)2 * 1024 * 1024);          // 4 MB
  float* sq   = (float*)(ws + (size_t)6 * 1024 * 1024);          // 64 KB
  ushort* cand = (ushort*)(ws + (size_t)6 * 1024 * 1024 + 65536);           // 2.62 MB
  char* after_cand = ws + (size_t)6 * 1024 * 1024 + 65536 + (size_t)16384 * 2 * QCAP * 2;
  int* knn    = (int*)after_cand;                                 // 1.11 MB
  ushort* ccnt = (ushort*)(after_cand + (size_t)BATCH * KOUT * NPTS * 4);   // 64 KB

  float* idxf = out + (size_t)BATCH * 2 * DIM * KOUT * NPTS;

  prep_kernel<<<512, 256, 0, stream>>>(pc, phl, pct, sq);
  knn_kernel<<<1024, 256, 0, stream>>>(phl, sq, cand, ccnt);
  refine_kernel<<<4096, 256, 0, stream>>>(pct, cand, ccnt, knn, idxf);
  edge_kernel<<<dim3(NPTS / 1024, BATCH * DIM), 256, 0, stream>>>(pc, knn, out);
}